// Round 2
// baseline (1600.997 us; speedup 1.0000x reference)
//
#include <hip/hip_runtime.h>

#define EPSF 1e-6f

// Zero the accumulator (capture-safe, no hipMemsetAsync).
__global__ __launch_bounds__(256) void zero_kernel(float4* __restrict__ acc, int n4)
{
    int i = blockIdx.x * blockDim.x + threadIdx.x;
    if (i < n4) acc[i] = make_float4(0.f, 0.f, 0.f, 0.f);
}

// Edge kernel: one thread per edge (grid-stride).
// acc layout: float4 per vertex = {sum0, sum1, sum2, count}
__global__ __launch_bounds__(256) void edge_kernel(
    const float* __restrict__ vertices,
    const int2*  __restrict__ edges,
    const float4* __restrict__ messages,   // E * 2 float4 (8 floats per edge)
    float* __restrict__ acc,
    int E)
{
    int stride = gridDim.x * blockDim.x;
    for (int e = blockIdx.x * blockDim.x + threadIdx.x; e < E; e += stride) {
        int2 ed = edges[e];
        float4 m0 = messages[2 * e];
        float4 m1 = messages[2 * e + 1];
        float wgt = (((m0.x + m0.y) + (m0.z + m0.w)) +
                     ((m1.x + m1.y) + (m1.z + m1.w))) * 0.125f;

        const float* xp = vertices + 3 * (size_t)ed.x;
        const float* yp = vertices + 3 * (size_t)ed.y;
        float x0 = xp[0], x1 = xp[1], x2 = xp[2];
        float y0 = yp[0], y1 = yp[1], y2 = yp[2];

        // Minkowski inner product, w = (-1, 1, 1); K = 1
        float t  = x1 * y1 + x2 * y2 - x0 * y0;
        float v0 = y0 + x0 * t;
        float v1 = y1 + x1 * t;
        float v2 = y2 + x2 * t;
        float mipv = v1 * v1 + v2 * v2 - v0 * v0;
        float vn   = sqrtf(mipv + EPSF);
        float dist = acoshf(-t);
        float scale = dist * wgt / vn;

        float* a = acc + 4 * (size_t)ed.x;
        atomicAdd(a + 0, v0 * scale);
        atomicAdd(a + 1, v1 * scale);
        atomicAdd(a + 2, v2 * scale);
        atomicAdd(a + 3, 1.0f);
    }
}

// Vertex kernel: normalize aggregate and apply exp-map.
__global__ __launch_bounds__(256) void vertex_kernel(
    const float* __restrict__ vertices,
    const float4* __restrict__ acc,
    float* __restrict__ out,
    int N)
{
    int i = blockIdx.x * blockDim.x + threadIdx.x;
    if (i >= N) return;
    float4 a = acc[i];
    float g0 = 0.f, g1 = 0.f, g2 = 0.f;
    if (a.w > 0.f) {
        g0 = a.x / a.w;
        g1 = a.y / a.w;
        g2 = a.z / a.w;
    }
    float an = sqrtf(g1 * g1 + g2 * g2 - g0 * g0 + EPSF);
    float ch = coshf(an);
    float sh = sinhf(an) / an;   // sqrt(K) = 1
    size_t b = 3 * (size_t)i;
    out[b + 0] = ch * vertices[b + 0] + sh * g0;
    out[b + 1] = ch * vertices[b + 1] + sh * g1;
    out[b + 2] = ch * vertices[b + 2] + sh * g2;
}

extern "C" void kernel_launch(void* const* d_in, const int* in_sizes, int n_in,
                              void* d_out, int out_size, void* d_ws, size_t ws_size,
                              hipStream_t stream)
{
    const float*  vertices = (const float*)d_in[0];
    const int2*   edges    = (const int2*)d_in[1];
    const float4* messages = (const float4*)d_in[2];
    float* out = (float*)d_out;

    int N = in_sizes[0] / 3;   // 500000
    int E = in_sizes[1] / 2;   // 8000000

    float* acc = (float*)d_ws; // N * float4 = 8 MB

    const int blk = 256;
    zero_kernel<<<(N + blk - 1) / blk, blk, 0, stream>>>((float4*)acc, N);
    edge_kernel<<<4096, blk, 0, stream>>>(vertices, edges, messages, acc, E);
    vertex_kernel<<<(N + blk - 1) / blk, blk, 0, stream>>>(vertices, (const float4*)acc, out, N);
}